// Round 1
// baseline (1816.214 us; speedup 1.0000x reference)
//
#include <hip/hip_runtime.h>
#include <hip/hip_bf16.h>
#include <math.h>

// Problem constants (from reference): N=20000, E=320000, DIM=768, HEADS=8/1.
#define DIM 768

// ---------------------------------------------------------------------------
// CSR build: histogram of dst, exclusive scan, scatter src ids into dst-order
// ---------------------------------------------------------------------------
__global__ __launch_bounds__(256) void hist_kernel(const int* __restrict__ dst,
                                                   int* __restrict__ deg, int E) {
    int e = blockIdx.x * 256 + threadIdx.x;
    if (e < E) atomicAdd(&deg[dst[e]], 1);
}

__global__ __launch_bounds__(1024) void scan_kernel(const int* __restrict__ deg,
                                                    int* __restrict__ row_start,
                                                    int* __restrict__ cursor, int n) {
    __shared__ int sh[1024];
    __shared__ int carry_sh;
    int tid = threadIdx.x;
    if (tid == 0) carry_sh = 0;
    __syncthreads();
    for (int base = 0; base < n; base += 1024) {
        int i = base + tid;
        int v = (i < n) ? deg[i] : 0;
        sh[tid] = v;
        __syncthreads();
        for (int off = 1; off < 1024; off <<= 1) {
            int t = (tid >= off) ? sh[tid - off] : 0;
            __syncthreads();
            sh[tid] += t;
            __syncthreads();
        }
        int incl = sh[tid];
        int carry = carry_sh;
        int excl = carry + incl - v;
        if (i < n) { row_start[i] = excl; cursor[i] = excl; }
        __syncthreads();
        if (tid == 1023) carry_sh = carry + incl;
        __syncthreads();
    }
    if (tid == 0) row_start[n] = carry_sh;
}

__global__ __launch_bounds__(256) void scatter_kernel(const int* __restrict__ src,
                                                      const int* __restrict__ dst,
                                                      int* __restrict__ cursor,
                                                      int* __restrict__ csr_src, int E) {
    int e = blockIdx.x * 256 + threadIdx.x;
    if (e < E) {
        int p = atomicAdd(&cursor[dst[e]], 1);
        csr_src[p] = src[e];
    }
}

// ---------------------------------------------------------------------------
// Dual fp32 GEMM: C1 = X*W1 + b1, C2 = X*W2 + b2.  X:[M,768] W:[768,768]
// 64x64 tile, BK=16, 256 threads, 4x4 micro-tile per thread (x2 outputs).
// ---------------------------------------------------------------------------
__global__ __launch_bounds__(256) void gemm_dual_kernel(
    const float* __restrict__ X,
    const float* __restrict__ W1, const float* __restrict__ b1,
    const float* __restrict__ W2, const float* __restrict__ b2,
    float* __restrict__ C1, float* __restrict__ C2, int M) {
    __shared__ float As[16][65];   // [k][m], padded
    __shared__ float Bs1[16][64];  // [k][n]
    __shared__ float Bs2[16][64];
    int bm = blockIdx.x * 64;
    int bn = blockIdx.y * 64;
    int tid = threadIdx.x;
    int tx = tid & 15, ty = tid >> 4;

    float acc1[4][4] = {};
    float acc2[4][4] = {};

    int lr = tid >> 2;           // 0..63 : X row in tile
    int lk = (tid & 3) * 4;      // 0,4,8,12 : k offset
    int wr = tid >> 4;           // 0..15 : W k-row
    int wc = (tid & 15) * 4;     // col offset

    for (int k0 = 0; k0 < DIM; k0 += 16) {
        float4 xa = make_float4(0.f, 0.f, 0.f, 0.f);
        if (bm + lr < M)
            xa = *reinterpret_cast<const float4*>(X + (size_t)(bm + lr) * DIM + k0 + lk);
        As[lk + 0][lr] = xa.x;
        As[lk + 1][lr] = xa.y;
        As[lk + 2][lr] = xa.z;
        As[lk + 3][lr] = xa.w;
        float4 w1 = *reinterpret_cast<const float4*>(W1 + (size_t)(k0 + wr) * DIM + bn + wc);
        float4 w2 = *reinterpret_cast<const float4*>(W2 + (size_t)(k0 + wr) * DIM + bn + wc);
        *reinterpret_cast<float4*>(&Bs1[wr][wc]) = w1;
        *reinterpret_cast<float4*>(&Bs2[wr][wc]) = w2;
        __syncthreads();
#pragma unroll
        for (int kk = 0; kk < 16; ++kk) {
            float a[4], u[4], v[4];
#pragma unroll
            for (int j = 0; j < 4; ++j) a[j] = As[kk][ty * 4 + j];
            float4 uu = *reinterpret_cast<const float4*>(&Bs1[kk][tx * 4]);
            float4 vv = *reinterpret_cast<const float4*>(&Bs2[kk][tx * 4]);
            u[0] = uu.x; u[1] = uu.y; u[2] = uu.z; u[3] = uu.w;
            v[0] = vv.x; v[1] = vv.y; v[2] = vv.z; v[3] = vv.w;
#pragma unroll
            for (int i = 0; i < 4; ++i)
#pragma unroll
                for (int j = 0; j < 4; ++j) {
                    acc1[i][j] = fmaf(a[i], u[j], acc1[i][j]);
                    acc2[i][j] = fmaf(a[i], v[j], acc2[i][j]);
                }
        }
        __syncthreads();
    }

    int row0 = bm + ty * 4;
    int col0 = bn + tx * 4;
    float4 bb1 = *reinterpret_cast<const float4*>(b1 + col0);
    float4 bb2 = *reinterpret_cast<const float4*>(b2 + col0);
#pragma unroll
    for (int i = 0; i < 4; ++i) {
        int r = row0 + i;
        if (r < M) {
            float4 o1 = make_float4(acc1[i][0] + bb1.x, acc1[i][1] + bb1.y,
                                    acc1[i][2] + bb1.z, acc1[i][3] + bb1.w);
            float4 o2 = make_float4(acc2[i][0] + bb2.x, acc2[i][1] + bb2.y,
                                    acc2[i][2] + bb2.z, acc2[i][3] + bb2.w);
            *reinterpret_cast<float4*>(C1 + (size_t)r * DIM + col0) = o1;
            *reinterpret_cast<float4*>(C2 + (size_t)r * DIM + col0) = o2;
        }
    }
}

// ---------------------------------------------------------------------------
// Per-node GAT kernel: one wave per destination node.
// Lane l owns dims [12l, 12l+12). Head group = 64/H contiguous lanes.
// Loop1: logits + per-head max. Loop2: ex, denom, unnormalized aggregate.
// Finalize: /denom -> ELU -> (+resid) -> LayerNorm -> out.
// ---------------------------------------------------------------------------
template <int H>
__global__ __launch_bounds__(256) void gat_node_kernel(
    const float* __restrict__ fs, const float* __restrict__ fd,
    const int* __restrict__ row_start, const int* __restrict__ csr_src,
    const float* __restrict__ attn,   // [H * (768/H)] == [768] flat
    const float* __restrict__ resid,  // residual input (x) or nullptr
    const float* __restrict__ ln_w, const float* __restrict__ ln_b,
    float* __restrict__ out, int n_nodes) {
    constexpr int G = 64 / H;  // lanes per head group
    int wave = threadIdx.x >> 6;
    int lane = threadIdx.x & 63;
    int node = blockIdx.x * 4 + wave;
    if (node >= n_nodes) return;
    int d0 = lane * 12;

    float fdv[12], av[12], agg[12];
    {
        const float4* p = reinterpret_cast<const float4*>(fd + (size_t)node * DIM + d0);
        float4 q0 = p[0], q1 = p[1], q2 = p[2];
        fdv[0] = q0.x; fdv[1] = q0.y; fdv[2] = q0.z; fdv[3] = q0.w;
        fdv[4] = q1.x; fdv[5] = q1.y; fdv[6] = q1.z; fdv[7] = q1.w;
        fdv[8] = q2.x; fdv[9] = q2.y; fdv[10] = q2.z; fdv[11] = q2.w;
    }
    {
        const float4* p = reinterpret_cast<const float4*>(attn + d0);
        float4 q0 = p[0], q1 = p[1], q2 = p[2];
        av[0] = q0.x; av[1] = q0.y; av[2] = q0.z; av[3] = q0.w;
        av[4] = q1.x; av[5] = q1.y; av[6] = q1.z; av[7] = q1.w;
        av[8] = q2.x; av[9] = q2.y; av[10] = q2.z; av[11] = q2.w;
    }
#pragma unroll
    for (int j = 0; j < 12; ++j) agg[j] = 0.f;

    int p0 = row_start[node], p1 = row_start[node + 1];
    float m = -INFINITY;

    // ---- loop 1: per-head max of logits over in-edges
    for (int p = p0; p < p1; ++p) {
        int s = csr_src[p];
        const float4* fp = reinterpret_cast<const float4*>(fs + (size_t)s * DIM + d0);
        float4 q0 = fp[0], q1 = fp[1], q2 = fp[2];
        float fv[12];
        fv[0] = q0.x; fv[1] = q0.y; fv[2] = q0.z; fv[3] = q0.w;
        fv[4] = q1.x; fv[5] = q1.y; fv[6] = q1.z; fv[7] = q1.w;
        fv[8] = q2.x; fv[9] = q2.y; fv[10] = q2.z; fv[11] = q2.w;
        float t = 0.f;
#pragma unroll
        for (int j = 0; j < 12; ++j) {
            float u = fv[j] + fdv[j];
            u = (u > 0.f) ? u : 0.2f * u;
            t = fmaf(u, av[j], t);
        }
#pragma unroll
        for (int off = 1; off < G; off <<= 1) t += __shfl_xor(t, off, 64);
        m = fmaxf(m, t);
    }

    // ---- loop 2: exp-sum and unnormalized aggregation
    float denom = 0.f;
    for (int p = p0; p < p1; ++p) {
        int s = csr_src[p];
        const float4* fp = reinterpret_cast<const float4*>(fs + (size_t)s * DIM + d0);
        float4 q0 = fp[0], q1 = fp[1], q2 = fp[2];
        float fv[12];
        fv[0] = q0.x; fv[1] = q0.y; fv[2] = q0.z; fv[3] = q0.w;
        fv[4] = q1.x; fv[5] = q1.y; fv[6] = q1.z; fv[7] = q1.w;
        fv[8] = q2.x; fv[9] = q2.y; fv[10] = q2.z; fv[11] = q2.w;
        float t = 0.f;
#pragma unroll
        for (int j = 0; j < 12; ++j) {
            float u = fv[j] + fdv[j];
            u = (u > 0.f) ? u : 0.2f * u;
            t = fmaf(u, av[j], t);
        }
#pragma unroll
        for (int off = 1; off < G; off <<= 1) t += __shfl_xor(t, off, 64);
        float ex = expf(t - m);
        denom += ex;
#pragma unroll
        for (int j = 0; j < 12; ++j) agg[j] = fmaf(ex, fv[j], agg[j]);
    }

    // ---- finalize: normalize, ELU, residual, LayerNorm
    float inv = (denom > 0.f) ? 1.0f / denom : 0.f;
    float vals[12];
#pragma unroll
    for (int j = 0; j < 12; ++j) {
        float v = agg[j] * inv;
        v = (v > 0.f) ? v : expm1f(v);
        vals[j] = v;
    }
    if (resid != nullptr) {
        const float4* p = reinterpret_cast<const float4*>(resid + (size_t)node * DIM + d0);
        float4 q0 = p[0], q1 = p[1], q2 = p[2];
        vals[0] += q0.x; vals[1] += q0.y; vals[2] += q0.z; vals[3] += q0.w;
        vals[4] += q1.x; vals[5] += q1.y; vals[6] += q1.z; vals[7] += q1.w;
        vals[8] += q2.x; vals[9] += q2.y; vals[10] += q2.z; vals[11] += q2.w;
    }
    float s1 = 0.f;
#pragma unroll
    for (int j = 0; j < 12; ++j) s1 += vals[j];
#pragma unroll
    for (int off = 1; off < 64; off <<= 1) s1 += __shfl_xor(s1, off, 64);
    float mu = s1 * (1.0f / DIM);
    float s2 = 0.f;
#pragma unroll
    for (int j = 0; j < 12; ++j) {
        float dlt = vals[j] - mu;
        s2 = fmaf(dlt, dlt, s2);
    }
#pragma unroll
    for (int off = 1; off < 64; off <<= 1) s2 += __shfl_xor(s2, off, 64);
    float rs = rsqrtf(s2 * (1.0f / DIM) + 1e-5f);

    float wv[12], bv[12];
    {
        const float4* p = reinterpret_cast<const float4*>(ln_w + d0);
        float4 q0 = p[0], q1 = p[1], q2 = p[2];
        wv[0] = q0.x; wv[1] = q0.y; wv[2] = q0.z; wv[3] = q0.w;
        wv[4] = q1.x; wv[5] = q1.y; wv[6] = q1.z; wv[7] = q1.w;
        wv[8] = q2.x; wv[9] = q2.y; wv[10] = q2.z; wv[11] = q2.w;
        const float4* pb = reinterpret_cast<const float4*>(ln_b + d0);
        float4 r0 = pb[0], r1 = pb[1], r2 = pb[2];
        bv[0] = r0.x; bv[1] = r0.y; bv[2] = r0.z; bv[3] = r0.w;
        bv[4] = r1.x; bv[5] = r1.y; bv[6] = r1.z; bv[7] = r1.w;
        bv[8] = r2.x; bv[9] = r2.y; bv[10] = r2.z; bv[11] = r2.w;
    }
    float* op = out + (size_t)node * DIM + d0;
#pragma unroll
    for (int q = 0; q < 3; ++q) {
        float4 o;
        o.x = (vals[q * 4 + 0] - mu) * rs * wv[q * 4 + 0] + bv[q * 4 + 0];
        o.y = (vals[q * 4 + 1] - mu) * rs * wv[q * 4 + 1] + bv[q * 4 + 1];
        o.z = (vals[q * 4 + 2] - mu) * rs * wv[q * 4 + 2] + bv[q * 4 + 2];
        o.w = (vals[q * 4 + 3] - mu) * rs * wv[q * 4 + 3] + bv[q * 4 + 3];
        *reinterpret_cast<float4*>(op + q * 4) = o;
    }
}

// ---------------------------------------------------------------------------
extern "C" void kernel_launch(void* const* d_in, const int* in_sizes, int n_in,
                              void* d_out, int out_size, void* d_ws, size_t ws_size,
                              hipStream_t stream) {
    const float* x     = (const float*)d_in[0];
    const int*   src   = (const int*)d_in[1];
    const int*   dst   = (const int*)d_in[2];
    const float* W1s   = (const float*)d_in[3];
    const float* b1s   = (const float*)d_in[4];
    const float* W1d   = (const float*)d_in[5];
    const float* b1d   = (const float*)d_in[6];
    const float* attn1 = (const float*)d_in[7];
    const float* ln1w  = (const float*)d_in[8];
    const float* ln1b  = (const float*)d_in[9];
    const float* Wos   = (const float*)d_in[10];
    const float* bos   = (const float*)d_in[11];
    const float* Wod   = (const float*)d_in[12];
    const float* bod   = (const float*)d_in[13];
    const float* attno = (const float*)d_in[14];
    const float* lnow  = (const float*)d_in[15];
    const float* lnob  = (const float*)d_in[16];
    float* out = (float*)d_out;

    const int N = in_sizes[0] / DIM;   // 20000
    const int E = in_sizes[1];         // 320000

    // workspace layout (fp32): fs[N*768] fd[N*768] | csr_src[E] row_start[N+1] cursor[N] deg[N]
    float* fs = (float*)d_ws;
    float* fd = fs + (size_t)N * DIM;
    int* csr_src   = (int*)(fd + (size_t)N * DIM);
    int* row_start = csr_src + E;
    int* cursor    = row_start + (N + 1);
    int* deg       = cursor + N;

    // --- CSR by dst (shared by both layers)
    hipMemsetAsync(deg, 0, (size_t)N * sizeof(int), stream);
    hist_kernel<<<(E + 255) / 256, 256, 0, stream>>>(dst, deg, E);
    scan_kernel<<<1, 1024, 0, stream>>>(deg, row_start, cursor, N);
    scatter_kernel<<<(E + 255) / 256, 256, 0, stream>>>(src, dst, cursor, csr_src, E);

    dim3 gemm_grid((N + 63) / 64, DIM / 64);

    // --- layer 1 (8 heads x 96), residual = x, LN1 -> h (stored in d_out)
    gemm_dual_kernel<<<gemm_grid, 256, 0, stream>>>(x, W1s, b1s, W1d, b1d, fs, fd, N);
    gat_node_kernel<8><<<(N + 3) / 4, 256, 0, stream>>>(fs, fd, row_start, csr_src,
                                                        attn1, x, ln1w, ln1b, out, N);

    // --- layer 2 (1 head x 768), no residual, LNo -> d_out (overwrites h)
    gemm_dual_kernel<<<gemm_grid, 256, 0, stream>>>(out, Wos, bos, Wod, bod, fs, fd, N);
    gat_node_kernel<1><<<(N + 3) / 4, 256, 0, stream>>>(fs, fd, row_start, csr_src,
                                                        attno, nullptr, lnow, lnob, out, N);
}

// Round 2
// 633.085 us; speedup vs baseline: 2.8688x; 2.8688x over previous
//
#include <hip/hip_runtime.h>
#include <hip/hip_bf16.h>
#include <math.h>

#define DIM 768

typedef __bf16 bf16_t;
typedef __attribute__((ext_vector_type(8))) __bf16 bf16x8;
typedef __attribute__((ext_vector_type(4))) float f32x4;

#define GLOAD_LDS16(g, l)                                                  \
    __builtin_amdgcn_global_load_lds(                                      \
        (const __attribute__((address_space(1))) void*)(g),                \
        (__attribute__((address_space(3))) void*)(l), 16, 0, 0)

__device__ __forceinline__ float bf2f(unsigned short u) {
    union { unsigned int i; float f; } x;
    x.i = ((unsigned int)u) << 16;
    return x.f;
}

// ---------------------------------------------------------------------------
// CSR build: histogram of dst, exclusive scan, scatter src ids into dst-order
// ---------------------------------------------------------------------------
__global__ __launch_bounds__(256) void hist_kernel(const int* __restrict__ dst,
                                                   int* __restrict__ deg, int E) {
    int e = blockIdx.x * 256 + threadIdx.x;
    if (e < E) atomicAdd(&deg[dst[e]], 1);
}

__global__ __launch_bounds__(1024) void scan_kernel(const int* __restrict__ deg,
                                                    int* __restrict__ row_start,
                                                    int* __restrict__ cursor, int n) {
    __shared__ int sh[1024];
    __shared__ int carry_sh;
    int tid = threadIdx.x;
    if (tid == 0) carry_sh = 0;
    __syncthreads();
    for (int base = 0; base < n; base += 1024) {
        int i = base + tid;
        int v = (i < n) ? deg[i] : 0;
        sh[tid] = v;
        __syncthreads();
        for (int off = 1; off < 1024; off <<= 1) {
            int t = (tid >= off) ? sh[tid - off] : 0;
            __syncthreads();
            sh[tid] += t;
            __syncthreads();
        }
        int incl = sh[tid];
        int carry = carry_sh;
        int excl = carry + incl - v;
        if (i < n) { row_start[i] = excl; cursor[i] = excl; }
        __syncthreads();
        if (tid == 1023) carry_sh = carry + incl;
        __syncthreads();
    }
    if (tid == 0) row_start[n] = carry_sh;
}

__global__ __launch_bounds__(256) void scatter_kernel(const int* __restrict__ src,
                                                      const int* __restrict__ dst,
                                                      int* __restrict__ cursor,
                                                      int* __restrict__ csr_src, int E) {
    int e = blockIdx.x * 256 + threadIdx.x;
    if (e < E) {
        int p = atomicAdd(&cursor[dst[e]], 1);
        csr_src[p] = src[e];
    }
}

// ---------------------------------------------------------------------------
// fp32 -> bf16 elementwise convert (8 elems/thread)
// ---------------------------------------------------------------------------
__global__ __launch_bounds__(256) void conv_bf16_kernel(const float* __restrict__ in,
                                                        __hip_bfloat16* __restrict__ out,
                                                        int n8) {
    int i = blockIdx.x * 256 + threadIdx.x;
    if (i >= n8) return;
    const float4* p = reinterpret_cast<const float4*>(in + (size_t)i * 8);
    float4 a = p[0], b = p[1];
    __hip_bfloat16 v[8];
    v[0] = __float2bfloat16(a.x); v[1] = __float2bfloat16(a.y);
    v[2] = __float2bfloat16(a.z); v[3] = __float2bfloat16(a.w);
    v[4] = __float2bfloat16(b.x); v[5] = __float2bfloat16(b.y);
    v[6] = __float2bfloat16(b.z); v[7] = __float2bfloat16(b.w);
    *reinterpret_cast<uint4*>(out + (size_t)i * 8) = *reinterpret_cast<uint4*>(v);
}

// ---------------------------------------------------------------------------
// W [K][Nc] f32  ->  Wt [Nc][K] bf16  (tiled transpose)
// ---------------------------------------------------------------------------
__global__ __launch_bounds__(256) void transpose_bf16_kernel(const float* __restrict__ W,
                                                             __hip_bfloat16* __restrict__ Wt,
                                                             int K, int Nc) {
    __shared__ float tile[32][33];
    int bk = blockIdx.x * 32, bn = blockIdx.y * 32;
    int tx = threadIdx.x & 31, ty = threadIdx.x >> 5;  // 32 x 8
#pragma unroll
    for (int r = ty; r < 32; r += 8)
        tile[r][tx] = W[(size_t)(bk + r) * Nc + bn + tx];
    __syncthreads();
#pragma unroll
    for (int r = ty; r < 32; r += 8)
        Wt[(size_t)(bn + r) * K + bk + tx] = __float2bfloat16(tile[tx][r]);
}

// ---------------------------------------------------------------------------
// Dual bf16 MFMA GEMM: C = Xb[M,768] @ Wt^T + bias, N=1536 (two 768 halves).
// 128x128 tile, BK=64, 4 waves, 16x16x32 bf16 MFMA, XOR-swizzled LDS
// (pre-swizzled global source + swizzled ds_read), bias in acc init.
// Outputs bf16 (fs | fd).
// ---------------------------------------------------------------------------
__global__ __launch_bounds__(256) void gemm_mfma_dual_kernel(
    const bf16_t* __restrict__ Xb,   // [M][768]
    const bf16_t* __restrict__ Wt,   // [1536][768] (rows 0..767 = Ws^T, 768.. = Wd^T)
    const float* __restrict__ b1, const float* __restrict__ b2,
    __hip_bfloat16* __restrict__ C1, __hip_bfloat16* __restrict__ C2, int M) {
    __shared__ __align__(16) bf16_t As[128 * 64];
    __shared__ __align__(16) bf16_t Bs[128 * 64];

    const int tid = threadIdx.x;
    const int lane = tid & 63;
    const int w = tid >> 6;
    const int wr = w >> 1, wc = w & 1;
    const int bm = blockIdx.x * 128;
    const int bn = blockIdx.y * 128;  // 0..1535

    f32x4 acc[4][4];
    {
        const float* bp = (bn < DIM) ? b1 : b2;
        int cb = (bn < DIM) ? bn : bn - DIM;
#pragma unroll
        for (int ni = 0; ni < 4; ++ni) {
            float bv = bp[cb + wc * 64 + ni * 16 + (lane & 15)];
#pragma unroll
            for (int mi = 0; mi < 4; ++mi) acc[mi][ni] = f32x4{bv, bv, bv, bv};
        }
    }

    const int srow = w * 32 + (lane >> 3);   // staged row within 128-tile (per instr +8)
    const int scol = (lane & 7) * 8;         // element col (16B) before swizzle

    for (int k0 = 0; k0 < DIM; k0 += 64) {
#pragma unroll
        for (int i = 0; i < 4; ++i) {
            int r = srow + i * 8;
            int col = scol ^ ((r & 7) << 3);  // pre-swizzled source (rule #21)
            int rg = bm + r; rg = rg < M ? rg : M - 1;
            GLOAD_LDS16(Xb + (size_t)rg * DIM + k0 + col, &As[(w * 32 + i * 8) * 64]);
        }
#pragma unroll
        for (int i = 0; i < 4; ++i) {
            int r = srow + i * 8;
            int col = scol ^ ((r & 7) << 3);
            GLOAD_LDS16(Wt + (size_t)(bn + r) * DIM + k0 + col, &Bs[(w * 32 + i * 8) * 64]);
        }
        __syncthreads();

#pragma unroll
        for (int kk = 0; kk < 2; ++kk) {
            bf16x8 af[4], bfr[4];
            int ke = kk * 32 + (lane >> 4) * 8;
#pragma unroll
            for (int mi = 0; mi < 4; ++mi) {
                int r = wr * 64 + mi * 16 + (lane & 15);
                af[mi] = *(const bf16x8*)&As[r * 64 + (ke ^ ((r & 7) << 3))];
            }
#pragma unroll
            for (int ni = 0; ni < 4; ++ni) {
                int r = wc * 64 + ni * 16 + (lane & 15);
                bfr[ni] = *(const bf16x8*)&Bs[r * 64 + (ke ^ ((r & 7) << 3))];
            }
#pragma unroll
            for (int mi = 0; mi < 4; ++mi)
#pragma unroll
                for (int ni = 0; ni < 4; ++ni)
                    acc[mi][ni] = __builtin_amdgcn_mfma_f32_16x16x32_bf16(
                        af[mi], bfr[ni], acc[mi][ni], 0, 0, 0);
        }
        __syncthreads();
    }

    __hip_bfloat16* C = (bn < DIM) ? C1 : C2;
    int cb = (bn < DIM) ? bn : bn - DIM;
#pragma unroll
    for (int mi = 0; mi < 4; ++mi) {
#pragma unroll
        for (int j = 0; j < 4; ++j) {
            int row = bm + wr * 64 + mi * 16 + (lane >> 4) * 4 + j;
            if (row < M) {
#pragma unroll
                for (int ni = 0; ni < 4; ++ni) {
                    int col = cb + wc * 64 + ni * 16 + (lane & 15);
                    C[(size_t)row * DIM + col] = __float2bfloat16(acc[mi][ni][j]);
                }
            }
        }
    }
}

// ---------------------------------------------------------------------------
// Per-node GAT kernel: one wave per destination node; fs/fd are bf16.
// ---------------------------------------------------------------------------
__device__ __forceinline__ void load12(const unsigned short* __restrict__ p, float* v) {
    ushort4 a = *reinterpret_cast<const ushort4*>(p);
    ushort4 b = *reinterpret_cast<const ushort4*>(p + 4);
    ushort4 c = *reinterpret_cast<const ushort4*>(p + 8);
    v[0] = bf2f(a.x); v[1] = bf2f(a.y); v[2] = bf2f(a.z); v[3] = bf2f(a.w);
    v[4] = bf2f(b.x); v[5] = bf2f(b.y); v[6] = bf2f(b.z); v[7] = bf2f(b.w);
    v[8] = bf2f(c.x); v[9] = bf2f(c.y); v[10] = bf2f(c.z); v[11] = bf2f(c.w);
}

template <int H>
__global__ __launch_bounds__(256) void gat_node_kernel(
    const unsigned short* __restrict__ fs, const unsigned short* __restrict__ fd,
    const int* __restrict__ row_start, const int* __restrict__ csr_src,
    const float* __restrict__ attn, const float* __restrict__ resid,
    const float* __restrict__ ln_w, const float* __restrict__ ln_b,
    float* __restrict__ out, int n_nodes) {
    constexpr int G = 64 / H;
    int wave = threadIdx.x >> 6;
    int lane = threadIdx.x & 63;
    int node = blockIdx.x * 4 + wave;
    if (node >= n_nodes) return;
    int d0 = lane * 12;

    float fdv[12], av[12], agg[12];
    load12(fd + (size_t)node * DIM + d0, fdv);
    {
        const float4* p = reinterpret_cast<const float4*>(attn + d0);
        float4 q0 = p[0], q1 = p[1], q2 = p[2];
        av[0] = q0.x; av[1] = q0.y; av[2] = q0.z; av[3] = q0.w;
        av[4] = q1.x; av[5] = q1.y; av[6] = q1.z; av[7] = q1.w;
        av[8] = q2.x; av[9] = q2.y; av[10] = q2.z; av[11] = q2.w;
    }
#pragma unroll
    for (int j = 0; j < 12; ++j) agg[j] = 0.f;

    int p0 = row_start[node], p1 = row_start[node + 1];
    float m = -INFINITY;

    for (int p = p0; p < p1; ++p) {
        int s = csr_src[p];
        float fv[12];
        load12(fs + (size_t)s * DIM + d0, fv);
        float t = 0.f;
#pragma unroll
        for (int j = 0; j < 12; ++j) {
            float u = fv[j] + fdv[j];
            u = (u > 0.f) ? u : 0.2f * u;
            t = fmaf(u, av[j], t);
        }
#pragma unroll
        for (int off = 1; off < G; off <<= 1) t += __shfl_xor(t, off, 64);
        m = fmaxf(m, t);
    }

    float denom = 0.f;
    for (int p = p0; p < p1; ++p) {
        int s = csr_src[p];
        float fv[12];
        load12(fs + (size_t)s * DIM + d0, fv);
        float t = 0.f;
#pragma unroll
        for (int j = 0; j < 12; ++j) {
            float u = fv[j] + fdv[j];
            u = (u > 0.f) ? u : 0.2f * u;
            t = fmaf(u, av[j], t);
        }
#pragma unroll
        for (int off = 1; off < G; off <<= 1) t += __shfl_xor(t, off, 64);
        float ex = expf(t - m);
        denom += ex;
#pragma unroll
        for (int j = 0; j < 12; ++j) agg[j] = fmaf(ex, fv[j], agg[j]);
    }

    float inv = (denom > 0.f) ? 1.0f / denom : 0.f;
    float vals[12];
#pragma unroll
    for (int j = 0; j < 12; ++j) {
        float v = agg[j] * inv;
        vals[j] = (v > 0.f) ? v : expm1f(v);
    }
    if (resid != nullptr) {
        const float4* p = reinterpret_cast<const float4*>(resid + (size_t)node * DIM + d0);
        float4 q0 = p[0], q1 = p[1], q2 = p[2];
        vals[0] += q0.x; vals[1] += q0.y; vals[2] += q0.z; vals[3] += q0.w;
        vals[4] += q1.x; vals[5] += q1.y; vals[6] += q1.z; vals[7] += q1.w;
        vals[8] += q2.x; vals[9] += q2.y; vals[10] += q2.z; vals[11] += q2.w;
    }
    float s1 = 0.f;
#pragma unroll
    for (int j = 0; j < 12; ++j) s1 += vals[j];
#pragma unroll
    for (int off = 1; off < 64; off <<= 1) s1 += __shfl_xor(s1, off, 64);
    float mu = s1 * (1.0f / DIM);
    float s2 = 0.f;
#pragma unroll
    for (int j = 0; j < 12; ++j) {
        float dlt = vals[j] - mu;
        s2 = fmaf(dlt, dlt, s2);
    }
#pragma unroll
    for (int off = 1; off < 64; off <<= 1) s2 += __shfl_xor(s2, off, 64);
    float rs = rsqrtf(s2 * (1.0f / DIM) + 1e-5f);

    float wv[12], bv[12];
    {
        const float4* p = reinterpret_cast<const float4*>(ln_w + d0);
        float4 q0 = p[0], q1 = p[1], q2 = p[2];
        wv[0] = q0.x; wv[1] = q0.y; wv[2] = q0.z; wv[3] = q0.w;
        wv[4] = q1.x; wv[5] = q1.y; wv[6] = q1.z; wv[7] = q1.w;
        wv[8] = q2.x; wv[9] = q2.y; wv[10] = q2.z; wv[11] = q2.w;
        const float4* pb = reinterpret_cast<const float4*>(ln_b + d0);
        float4 r0 = pb[0], r1 = pb[1], r2 = pb[2];
        bv[0] = r0.x; bv[1] = r0.y; bv[2] = r0.z; bv[3] = r0.w;
        bv[4] = r1.x; bv[5] = r1.y; bv[6] = r1.z; bv[7] = r1.w;
        bv[8] = r2.x; bv[9] = r2.y; bv[10] = r2.z; bv[11] = r2.w;
    }
    float* op = out + (size_t)node * DIM + d0;
#pragma unroll
    for (int q = 0; q < 3; ++q) {
        float4 o;
        o.x = (vals[q * 4 + 0] - mu) * rs * wv[q * 4 + 0] + bv[q * 4 + 0];
        o.y = (vals[q * 4 + 1] - mu) * rs * wv[q * 4 + 1] + bv[q * 4 + 1];
        o.z = (vals[q * 4 + 2] - mu) * rs * wv[q * 4 + 2] + bv[q * 4 + 2];
        o.w = (vals[q * 4 + 3] - mu) * rs * wv[q * 4 + 3] + bv[q * 4 + 3];
        *reinterpret_cast<float4*>(op + q * 4) = o;
    }
}

// ---------------------------------------------------------------------------
extern "C" void kernel_launch(void* const* d_in, const int* in_sizes, int n_in,
                              void* d_out, int out_size, void* d_ws, size_t ws_size,
                              hipStream_t stream) {
    const float* x     = (const float*)d_in[0];
    const int*   src   = (const int*)d_in[1];
    const int*   dst   = (const int*)d_in[2];
    const float* W1s   = (const float*)d_in[3];
    const float* b1s   = (const float*)d_in[4];
    const float* W1d   = (const float*)d_in[5];
    const float* b1d   = (const float*)d_in[6];
    const float* attn1 = (const float*)d_in[7];
    const float* ln1w  = (const float*)d_in[8];
    const float* ln1b  = (const float*)d_in[9];
    const float* Wos   = (const float*)d_in[10];
    const float* bos   = (const float*)d_in[11];
    const float* Wod   = (const float*)d_in[12];
    const float* bod   = (const float*)d_in[13];
    const float* attno = (const float*)d_in[14];
    const float* lnow  = (const float*)d_in[15];
    const float* lnob  = (const float*)d_in[16];
    float* out = (float*)d_out;

    const int N = in_sizes[0] / DIM;   // 20000
    const int E = in_sizes[1];         // 320000

    // ws layout: fsb[N*768]bf16 fdb[N*768]bf16 Xb[N*768]bf16 W1t[1536*768]bf16
    //            Wot[1536*768]bf16 | csr_src[E] row_start[N+1] cursor[N] deg[N]
    __hip_bfloat16* fsb = (__hip_bfloat16*)d_ws;
    __hip_bfloat16* fdb = fsb + (size_t)N * DIM;
    __hip_bfloat16* Xb  = fdb + (size_t)N * DIM;
    __hip_bfloat16* W1t = Xb + (size_t)N * DIM;
    __hip_bfloat16* Wot = W1t + (size_t)2 * DIM * DIM;
    int* csr_src   = (int*)(Wot + (size_t)2 * DIM * DIM);
    int* row_start = csr_src + E;
    int* cursor    = row_start + (N + 1);
    int* deg       = cursor + N;

    // --- CSR by dst (shared by both layers)
    hipMemsetAsync(deg, 0, (size_t)N * sizeof(int), stream);
    hist_kernel<<<(E + 255) / 256, 256, 0, stream>>>(dst, deg, E);
    scan_kernel<<<1, 1024, 0, stream>>>(deg, row_start, cursor, N);
    scatter_kernel<<<(E + 255) / 256, 256, 0, stream>>>(src, dst, cursor, csr_src, E);

    // --- weight transposes (f32 -> bf16, [K][N] -> [N][K])
    dim3 tg(DIM / 32, DIM / 32);
    transpose_bf16_kernel<<<tg, 256, 0, stream>>>(W1s, W1t, DIM, DIM);
    transpose_bf16_kernel<<<tg, 256, 0, stream>>>(W1d, W1t + (size_t)DIM * DIM, DIM, DIM);
    transpose_bf16_kernel<<<tg, 256, 0, stream>>>(Wos, Wot, DIM, DIM);
    transpose_bf16_kernel<<<tg, 256, 0, stream>>>(Wod, Wot + (size_t)DIM * DIM, DIM, DIM);

    const int n8 = N * DIM / 8;
    dim3 gemm_grid((N + 127) / 128, 1536 / 128);

    // --- layer 1
    conv_bf16_kernel<<<(n8 + 255) / 256, 256, 0, stream>>>(x, Xb, n8);
    gemm_mfma_dual_kernel<<<gemm_grid, 256, 0, stream>>>(
        (const bf16_t*)Xb, (const bf16_t*)W1t, b1s, b1d, fsb, fdb, N);
    gat_node_kernel<8><<<(N + 3) / 4, 256, 0, stream>>>(
        (const unsigned short*)fsb, (const unsigned short*)fdb, row_start, csr_src,
        attn1, x, ln1w, ln1b, out, N);

    // --- layer 2
    conv_bf16_kernel<<<(n8 + 255) / 256, 256, 0, stream>>>(out, Xb, n8);
    gemm_mfma_dual_kernel<<<gemm_grid, 256, 0, stream>>>(
        (const bf16_t*)Xb, (const bf16_t*)Wot, bos, bod, fsb, fdb, N);
    gat_node_kernel<1><<<(N + 3) / 4, 256, 0, stream>>>(
        (const unsigned short*)fsb, (const unsigned short*)fdb, row_start, csr_src,
        attno, nullptr, lnow, lnob, out, N);
}

// Round 3
// 476.205 us; speedup vs baseline: 3.8139x; 1.3294x over previous
//
#include <hip/hip_runtime.h>
#include <hip/hip_bf16.h>
#include <math.h>

#define DIM 768

typedef __bf16 bf16_t;
typedef __attribute__((ext_vector_type(8))) __bf16 bf16x8;
typedef __attribute__((ext_vector_type(4))) float f32x4;

#define GLOAD_LDS16(g, l)                                                  \
    __builtin_amdgcn_global_load_lds(                                      \
        (const __attribute__((address_space(1))) void*)(g),                \
        (__attribute__((address_space(3))) void*)(l), 16, 0, 0)

__device__ __forceinline__ float bf2f(unsigned short u) {
    union { unsigned int i; float f; } x;
    x.i = ((unsigned int)u) << 16;
    return x.f;
}

// ---------------------------------------------------------------------------
// CSR build
// ---------------------------------------------------------------------------
__global__ __launch_bounds__(256) void hist_kernel(const int* __restrict__ dst,
                                                   int* __restrict__ deg, int E) {
    int e = blockIdx.x * 256 + threadIdx.x;
    if (e < E) atomicAdd(&deg[dst[e]], 1);
}

__global__ __launch_bounds__(1024) void scan_kernel(const int* __restrict__ deg,
                                                    int* __restrict__ row_start,
                                                    int* __restrict__ cursor, int n) {
    __shared__ int sh[1024];
    __shared__ int carry_sh;
    int tid = threadIdx.x;
    if (tid == 0) carry_sh = 0;
    __syncthreads();
    for (int base = 0; base < n; base += 1024) {
        int i = base + tid;
        int v = (i < n) ? deg[i] : 0;
        sh[tid] = v;
        __syncthreads();
        for (int off = 1; off < 1024; off <<= 1) {
            int t = (tid >= off) ? sh[tid - off] : 0;
            __syncthreads();
            sh[tid] += t;
            __syncthreads();
        }
        int incl = sh[tid];
        int carry = carry_sh;
        int excl = carry + incl - v;
        if (i < n) { row_start[i] = excl; cursor[i] = excl; }
        __syncthreads();
        if (tid == 1023) carry_sh = carry + incl;
        __syncthreads();
    }
    if (tid == 0) row_start[n] = carry_sh;
}

__global__ __launch_bounds__(256) void scatter_kernel(const int* __restrict__ src,
                                                      const int* __restrict__ dst,
                                                      int* __restrict__ cursor,
                                                      int* __restrict__ csr_src, int E) {
    int e = blockIdx.x * 256 + threadIdx.x;
    if (e < E) {
        int p = atomicAdd(&cursor[dst[e]], 1);
        csr_src[p] = src[e];
    }
}

// ---------------------------------------------------------------------------
// fp32 -> bf16 elementwise convert (8 elems/thread)
// ---------------------------------------------------------------------------
__global__ __launch_bounds__(256) void conv_bf16_kernel(const float* __restrict__ in,
                                                        __hip_bfloat16* __restrict__ out,
                                                        int n8) {
    int i = blockIdx.x * 256 + threadIdx.x;
    if (i >= n8) return;
    const float4* p = reinterpret_cast<const float4*>(in + (size_t)i * 8);
    float4 a = p[0], b = p[1];
    __hip_bfloat16 v[8];
    v[0] = __float2bfloat16(a.x); v[1] = __float2bfloat16(a.y);
    v[2] = __float2bfloat16(a.z); v[3] = __float2bfloat16(a.w);
    v[4] = __float2bfloat16(b.x); v[5] = __float2bfloat16(b.y);
    v[6] = __float2bfloat16(b.z); v[7] = __float2bfloat16(b.w);
    *reinterpret_cast<uint4*>(out + (size_t)i * 8) = *reinterpret_cast<uint4*>(v);
}

// ---------------------------------------------------------------------------
// W [K][Nc] f32  ->  Wt [Nc][K] bf16  (tiled transpose)
// ---------------------------------------------------------------------------
__global__ __launch_bounds__(256) void transpose_bf16_kernel(const float* __restrict__ W,
                                                             __hip_bfloat16* __restrict__ Wt,
                                                             int K, int Nc) {
    __shared__ float tile[32][33];
    int bk = blockIdx.x * 32, bn = blockIdx.y * 32;
    int tx = threadIdx.x & 31, ty = threadIdx.x >> 5;  // 32 x 8
#pragma unroll
    for (int r = ty; r < 32; r += 8)
        tile[r][tx] = W[(size_t)(bk + r) * Nc + bn + tx];
    __syncthreads();
#pragma unroll
    for (int r = ty; r < 32; r += 8)
        Wt[(size_t)(bn + r) * K + bk + tx] = __float2bfloat16(tile[tx][r]);
}

// ---------------------------------------------------------------------------
// Dual bf16 MFMA GEMM (unchanged from round 2)
// ---------------------------------------------------------------------------
__global__ __launch_bounds__(256) void gemm_mfma_dual_kernel(
    const bf16_t* __restrict__ Xb,   // [M][768]
    const bf16_t* __restrict__ Wt,   // [1536][768]
    const float* __restrict__ b1, const float* __restrict__ b2,
    __hip_bfloat16* __restrict__ C1, __hip_bfloat16* __restrict__ C2, int M) {
    __shared__ __align__(16) bf16_t As[128 * 64];
    __shared__ __align__(16) bf16_t Bs[128 * 64];

    const int tid = threadIdx.x;
    const int lane = tid & 63;
    const int w = tid >> 6;
    const int wr = w >> 1, wc = w & 1;
    const int bm = blockIdx.x * 128;
    const int bn = blockIdx.y * 128;

    f32x4 acc[4][4];
    {
        const float* bp = (bn < DIM) ? b1 : b2;
        int cb = (bn < DIM) ? bn : bn - DIM;
#pragma unroll
        for (int ni = 0; ni < 4; ++ni) {
            float bv = bp[cb + wc * 64 + ni * 16 + (lane & 15)];
#pragma unroll
            for (int mi = 0; mi < 4; ++mi) acc[mi][ni] = f32x4{bv, bv, bv, bv};
        }
    }

    const int srow = w * 32 + (lane >> 3);
    const int scol = (lane & 7) * 8;

    for (int k0 = 0; k0 < DIM; k0 += 64) {
#pragma unroll
        for (int i = 0; i < 4; ++i) {
            int r = srow + i * 8;
            int col = scol ^ ((r & 7) << 3);
            int rg = bm + r; rg = rg < M ? rg : M - 1;
            GLOAD_LDS16(Xb + (size_t)rg * DIM + k0 + col, &As[(w * 32 + i * 8) * 64]);
        }
#pragma unroll
        for (int i = 0; i < 4; ++i) {
            int r = srow + i * 8;
            int col = scol ^ ((r & 7) << 3);
            GLOAD_LDS16(Wt + (size_t)(bn + r) * DIM + k0 + col, &Bs[(w * 32 + i * 8) * 64]);
        }
        __syncthreads();

#pragma unroll
        for (int kk = 0; kk < 2; ++kk) {
            bf16x8 af[4], bfr[4];
            int ke = kk * 32 + (lane >> 4) * 8;
#pragma unroll
            for (int mi = 0; mi < 4; ++mi) {
                int r = wr * 64 + mi * 16 + (lane & 15);
                af[mi] = *(const bf16x8*)&As[r * 64 + (ke ^ ((r & 7) << 3))];
            }
#pragma unroll
            for (int ni = 0; ni < 4; ++ni) {
                int r = wc * 64 + ni * 16 + (lane & 15);
                bfr[ni] = *(const bf16x8*)&Bs[r * 64 + (ke ^ ((r & 7) << 3))];
            }
#pragma unroll
            for (int mi = 0; mi < 4; ++mi)
#pragma unroll
                for (int ni = 0; ni < 4; ++ni)
                    acc[mi][ni] = __builtin_amdgcn_mfma_f32_16x16x32_bf16(
                        af[mi], bfr[ni], acc[mi][ni], 0, 0, 0);
        }
        __syncthreads();
    }

    __hip_bfloat16* C = (bn < DIM) ? C1 : C2;
    int cb = (bn < DIM) ? bn : bn - DIM;
#pragma unroll
    for (int mi = 0; mi < 4; ++mi) {
#pragma unroll
        for (int j = 0; j < 4; ++j) {
            int row = bm + wr * 64 + mi * 16 + (lane >> 4) * 4 + j;
            if (row < M) {
#pragma unroll
                for (int ni = 0; ni < 4; ++ni) {
                    int col = cb + wc * 64 + ni * 16 + (lane & 15);
                    C[(size_t)row * DIM + col] = __float2bfloat16(acc[mi][ni][j]);
                }
            }
        }
    }
}

// ---------------------------------------------------------------------------
// Per-node GAT kernel: one wave per dst node, ONLINE softmax (single gather
// pass). Optional f32 and/or bf16 output.
// ---------------------------------------------------------------------------
__device__ __forceinline__ void load12(const unsigned short* __restrict__ p, float* v) {
    ushort4 a = *reinterpret_cast<const ushort4*>(p);
    ushort4 b = *reinterpret_cast<const ushort4*>(p + 4);
    ushort4 c = *reinterpret_cast<const ushort4*>(p + 8);
    v[0] = bf2f(a.x); v[1] = bf2f(a.y); v[2] = bf2f(a.z); v[3] = bf2f(a.w);
    v[4] = bf2f(b.x); v[5] = bf2f(b.y); v[6] = bf2f(b.z); v[7] = bf2f(b.w);
    v[8] = bf2f(c.x); v[9] = bf2f(c.y); v[10] = bf2f(c.z); v[11] = bf2f(c.w);
}

template <int H>
__global__ __launch_bounds__(256) void gat_node_kernel(
    const unsigned short* __restrict__ fs, const unsigned short* __restrict__ fd,
    const int* __restrict__ row_start, const int* __restrict__ csr_src,
    const float* __restrict__ attn, const float* __restrict__ resid,
    const float* __restrict__ ln_w, const float* __restrict__ ln_b,
    float* __restrict__ outf, __hip_bfloat16* __restrict__ outb, int n_nodes) {
    constexpr int G = 64 / H;
    int wave = threadIdx.x >> 6;
    int lane = threadIdx.x & 63;
    int node = blockIdx.x * 4 + wave;
    if (node >= n_nodes) return;
    int d0 = lane * 12;

    float fdv[12], av[12], agg[12];
    load12(fd + (size_t)node * DIM + d0, fdv);
    {
        const float4* p = reinterpret_cast<const float4*>(attn + d0);
        float4 q0 = p[0], q1 = p[1], q2 = p[2];
        av[0] = q0.x; av[1] = q0.y; av[2] = q0.z; av[3] = q0.w;
        av[4] = q1.x; av[5] = q1.y; av[6] = q1.z; av[7] = q1.w;
        av[8] = q2.x; av[9] = q2.y; av[10] = q2.z; av[11] = q2.w;
    }
#pragma unroll
    for (int j = 0; j < 12; ++j) agg[j] = 0.f;

    int p0 = row_start[node], p1 = row_start[node + 1];
    float m = -INFINITY;
    float denom = 0.f;

    int sNext = (p0 < p1) ? csr_src[p0] : 0;
    for (int p = p0; p < p1; ++p) {
        int s = sNext;
        sNext = (p + 1 < p1) ? csr_src[p + 1] : 0;
        float fv[12];
        load12(fs + (size_t)s * DIM + d0, fv);
        float t = 0.f;
#pragma unroll
        for (int j = 0; j < 12; ++j) {
            float u = fv[j] + fdv[j];
            u = (u > 0.f) ? u : 0.2f * u;
            t = fmaf(u, av[j], t);
        }
#pragma unroll
        for (int off = 1; off < G; off <<= 1) t += __shfl_xor(t, off, 64);
        // online softmax update (branchless; m=-inf start -> c=0 exact)
        float mn = fmaxf(m, t);
        float c  = __expf(m - mn);
        float ex = __expf(t - mn);
        denom = denom * c + ex;
#pragma unroll
        for (int j = 0; j < 12; ++j) agg[j] = fmaf(agg[j], c, ex * fv[j]);
        m = mn;
    }

    float inv = (denom > 0.f) ? 1.0f / denom : 0.f;
    float vals[12];
#pragma unroll
    for (int j = 0; j < 12; ++j) {
        float v = agg[j] * inv;
        vals[j] = (v > 0.f) ? v : expm1f(v);
    }
    if (resid != nullptr) {
        const float4* p = reinterpret_cast<const float4*>(resid + (size_t)node * DIM + d0);
        float4 q0 = p[0], q1 = p[1], q2 = p[2];
        vals[0] += q0.x; vals[1] += q0.y; vals[2] += q0.z; vals[3] += q0.w;
        vals[4] += q1.x; vals[5] += q1.y; vals[6] += q1.z; vals[7] += q1.w;
        vals[8] += q2.x; vals[9] += q2.y; vals[10] += q2.z; vals[11] += q2.w;
    }
    float s1 = 0.f;
#pragma unroll
    for (int j = 0; j < 12; ++j) s1 += vals[j];
#pragma unroll
    for (int off = 1; off < 64; off <<= 1) s1 += __shfl_xor(s1, off, 64);
    float mu = s1 * (1.0f / DIM);
    float s2 = 0.f;
#pragma unroll
    for (int j = 0; j < 12; ++j) {
        float dlt = vals[j] - mu;
        s2 = fmaf(dlt, dlt, s2);
    }
#pragma unroll
    for (int off = 1; off < 64; off <<= 1) s2 += __shfl_xor(s2, off, 64);
    float rs = rsqrtf(s2 * (1.0f / DIM) + 1e-5f);

    float wv[12], bv[12];
    {
        const float4* p = reinterpret_cast<const float4*>(ln_w + d0);
        float4 q0 = p[0], q1 = p[1], q2 = p[2];
        wv[0] = q0.x; wv[1] = q0.y; wv[2] = q0.z; wv[3] = q0.w;
        wv[4] = q1.x; wv[5] = q1.y; wv[6] = q1.z; wv[7] = q1.w;
        wv[8] = q2.x; wv[9] = q2.y; wv[10] = q2.z; wv[11] = q2.w;
        const float4* pb = reinterpret_cast<const float4*>(ln_b + d0);
        float4 r0 = pb[0], r1 = pb[1], r2 = pb[2];
        bv[0] = r0.x; bv[1] = r0.y; bv[2] = r0.z; bv[3] = r0.w;
        bv[4] = r1.x; bv[5] = r1.y; bv[6] = r1.z; bv[7] = r1.w;
        bv[8] = r2.x; bv[9] = r2.y; bv[10] = r2.z; bv[11] = r2.w;
    }
    float o[12];
#pragma unroll
    for (int j = 0; j < 12; ++j)
        o[j] = (vals[j] - mu) * rs * wv[j] + bv[j];

    if (outf != nullptr) {
        float* op = outf + (size_t)node * DIM + d0;
#pragma unroll
        for (int q = 0; q < 3; ++q) {
            float4 t4 = make_float4(o[q * 4 + 0], o[q * 4 + 1], o[q * 4 + 2], o[q * 4 + 3]);
            *reinterpret_cast<float4*>(op + q * 4) = t4;
        }
    }
    if (outb != nullptr) {
        __hip_bfloat16 hb[12];
#pragma unroll
        for (int j = 0; j < 12; ++j) hb[j] = __float2bfloat16(o[j]);
        unsigned short* op = (unsigned short*)outb + (size_t)node * DIM + d0;
#pragma unroll
        for (int q = 0; q < 3; ++q)
            *reinterpret_cast<ushort4*>(op + q * 4) =
                *reinterpret_cast<ushort4*>(&hb[q * 4]);
    }
}

// ---------------------------------------------------------------------------
extern "C" void kernel_launch(void* const* d_in, const int* in_sizes, int n_in,
                              void* d_out, int out_size, void* d_ws, size_t ws_size,
                              hipStream_t stream) {
    const float* x     = (const float*)d_in[0];
    const int*   src   = (const int*)d_in[1];
    const int*   dst   = (const int*)d_in[2];
    const float* W1s   = (const float*)d_in[3];
    const float* b1s   = (const float*)d_in[4];
    const float* W1d   = (const float*)d_in[5];
    const float* b1d   = (const float*)d_in[6];
    const float* attn1 = (const float*)d_in[7];
    const float* ln1w  = (const float*)d_in[8];
    const float* ln1b  = (const float*)d_in[9];
    const float* Wos   = (const float*)d_in[10];
    const float* bos   = (const float*)d_in[11];
    const float* Wod   = (const float*)d_in[12];
    const float* bod   = (const float*)d_in[13];
    const float* attno = (const float*)d_in[14];
    const float* lnow  = (const float*)d_in[15];
    const float* lnob  = (const float*)d_in[16];
    float* out = (float*)d_out;

    const int N = in_sizes[0] / DIM;   // 20000
    const int E = in_sizes[1];         // 320000

    __hip_bfloat16* fsb = (__hip_bfloat16*)d_ws;
    __hip_bfloat16* fdb = fsb + (size_t)N * DIM;
    __hip_bfloat16* Xb  = fdb + (size_t)N * DIM;
    __hip_bfloat16* W1t = Xb + (size_t)N * DIM;
    __hip_bfloat16* Wot = W1t + (size_t)2 * DIM * DIM;
    int* csr_src   = (int*)(Wot + (size_t)2 * DIM * DIM);
    int* row_start = csr_src + E;
    int* cursor    = row_start + (N + 1);
    int* deg       = cursor + N;

    // --- CSR by dst (shared by both layers)
    hipMemsetAsync(deg, 0, (size_t)N * sizeof(int), stream);
    hist_kernel<<<(E + 255) / 256, 256, 0, stream>>>(dst, deg, E);
    scan_kernel<<<1, 1024, 0, stream>>>(deg, row_start, cursor, N);
    scatter_kernel<<<(E + 255) / 256, 256, 0, stream>>>(src, dst, cursor, csr_src, E);

    // --- weight transposes (f32 -> bf16, [K][N] -> [N][K])
    dim3 tg(DIM / 32, DIM / 32);
    transpose_bf16_kernel<<<tg, 256, 0, stream>>>(W1s, W1t, DIM, DIM);
    transpose_bf16_kernel<<<tg, 256, 0, stream>>>(W1d, W1t + (size_t)DIM * DIM, DIM, DIM);
    transpose_bf16_kernel<<<tg, 256, 0, stream>>>(Wos, Wot, DIM, DIM);
    transpose_bf16_kernel<<<tg, 256, 0, stream>>>(Wod, Wot + (size_t)DIM * DIM, DIM, DIM);

    const int n8 = N * DIM / 8;
    dim3 gemm_grid((N + 127) / 128, 1536 / 128);

    // --- layer 1: GEMM -> gat (writes bf16 h straight into Xb for layer 2)
    conv_bf16_kernel<<<(n8 + 255) / 256, 256, 0, stream>>>(x, Xb, n8);
    gemm_mfma_dual_kernel<<<gemm_grid, 256, 0, stream>>>(
        (const bf16_t*)Xb, (const bf16_t*)W1t, b1s, b1d, fsb, fdb, N);
    gat_node_kernel<8><<<(N + 3) / 4, 256, 0, stream>>>(
        (const unsigned short*)fsb, (const unsigned short*)fdb, row_start, csr_src,
        attn1, x, ln1w, ln1b, nullptr, Xb, N);

    // --- layer 2: GEMM -> gat -> final f32 out
    gemm_mfma_dual_kernel<<<gemm_grid, 256, 0, stream>>>(
        (const bf16_t*)Xb, (const bf16_t*)Wot, bos, bod, fsb, fdb, N);
    gat_node_kernel<1><<<(N + 3) / 4, 256, 0, stream>>>(
        (const unsigned short*)fsb, (const unsigned short*)fdb, row_start, csr_src,
        attno, nullptr, lnow, lnob, out, nullptr, N);
}